// Round 13
// baseline (164.480 us; speedup 1.0000x reference)
//
#include <hip/hip_runtime.h>

// Sizes fixed by the problem.
#define Bz 4
#define Nn 8192
#define Dd 512
#define Ll 64
#define Pp 128
#define Ww 64
#define Ss 32
#define NW 4   // number of window starts per segment

// wpack bank-conflict pad (R9, proven): lanes q=0..3 read d in {i,128+i,...};
// padded byte base 16*(130q+i) -> disjoint bank groups.
#define WPI(d) ((d) + 2 * ((d) >> 7))

// ---------------------------------------------------------------------------
// pre1: fully parallel preprocessing, 332 blocks x 256 threads.
//   [0,128):   QKp[j][l][c] partials of z @ (Wq^T Wk), K-SPLIT 2-way:
//              block (m-tile, n-tile, kh) computes its half-K tile in LDS and
//              writes exclusive partial j = 2*(m0/64)+kh of 16. M1 never stored.
//   [128,256): Gp[j][l][c] partials of z @ (Wq^T W2), same scheme.
//   [256,320): WvoT[e,d] = sum_c Wv[c,e] Wo[d,c]  (full K, direct store)
//   [320,328): vb8[j] = partial Wq^T @ b2
//   [328,332): per-batch coord stats (mean + std ddof=1)
__global__ __launch_bounds__(256) void pre1(
    const float* __restrict__ coords, const float* __restrict__ b2,
    const float* __restrict__ Wq, const float* __restrict__ Wk,
    const float* __restrict__ W2,
    const float* __restrict__ Wv, const float* __restrict__ Wo,
    const float* __restrict__ z,
    float* __restrict__ cstats,
    float* __restrict__ QKp, float* __restrict__ Gp,
    float* __restrict__ WvoT, float* __restrict__ vb8) {
    __shared__ float As[64][68];    // [k][m], 272B rows (16B-aligned)
    __shared__ float Bs[64][68];    // [k][n]; post-loop: holds the C-tile
    __shared__ float b2s[64];
    __shared__ double dred[16];
    int bid = blockIdx.x, tid = threadIdx.x;
    int wv = tid >> 6, lane = tid & 63;

    if (bid < 256) {
        // ---------- QKp / Gp roles, K-split 2-way ----------
        int role01 = bid >> 7;          // 0=QKp(M1), 1=Gp(M2)
        int wb = bid & 127;
        int kh = wb >> 6;               // k-half: K in [kh*256, kh*256+256)
        int t  = wb & 63;
        int m0 = (t >> 3) * 64;
        int n0 = (t & 7) * 64;
        const float* Bmat = role01 ? W2 : Wk;
        int tx = tid & 15, ty = tid >> 4;       // 16x16 thread grid, 4x4 each
        float4 acc[4];
#pragma unroll
        for (int i = 0; i < 4; ++i) acc[i] = make_float4(0.f, 0.f, 0.f, 0.f);

        for (int k0 = kh * 256; k0 < kh * 256 + 256; k0 += 64) {
            {
                int kk = tid >> 4, q4 = (tid & 15) * 4;
#pragma unroll
                for (int i = 0; i < 4; ++i) {
                    int k = kk + 16 * i;
                    *(float4*)&As[k][q4] =
                        *(const float4*)&Wq[(size_t)(k0 + k) * Dd + m0 + q4];
                }
#pragma unroll
                for (int i = 0; i < 4; ++i) {
                    int k = kk + 16 * i;
                    *(float4*)&Bs[k][q4] =
                        *(const float4*)&Bmat[(size_t)(k0 + k) * Dd + n0 + q4];
                }
            }
            __syncthreads();
#pragma unroll 8
            for (int kk = 0; kk < 64; ++kk) {
                float4 a4 = *(const float4*)&As[kk][ty * 4];
                float4 b4 = *(const float4*)&Bs[kk][tx * 4];
                acc[0].x = fmaf(a4.x, b4.x, acc[0].x); acc[0].y = fmaf(a4.x, b4.y, acc[0].y);
                acc[0].z = fmaf(a4.x, b4.z, acc[0].z); acc[0].w = fmaf(a4.x, b4.w, acc[0].w);
                acc[1].x = fmaf(a4.y, b4.x, acc[1].x); acc[1].y = fmaf(a4.y, b4.y, acc[1].y);
                acc[1].z = fmaf(a4.y, b4.z, acc[1].z); acc[1].w = fmaf(a4.y, b4.w, acc[1].w);
                acc[2].x = fmaf(a4.z, b4.x, acc[2].x); acc[2].y = fmaf(a4.z, b4.y, acc[2].y);
                acc[2].z = fmaf(a4.z, b4.z, acc[2].z); acc[2].w = fmaf(a4.z, b4.w, acc[2].w);
                acc[3].x = fmaf(a4.w, b4.x, acc[3].x); acc[3].y = fmaf(a4.w, b4.y, acc[3].y);
                acc[3].z = fmaf(a4.w, b4.z, acc[3].z); acc[3].w = fmaf(a4.w, b4.w, acc[3].w);
            }
            __syncthreads();
        }
        // ---- z-weighted partial: P[l, n0+c] = sum_{d in m-tile} z[l,d] * Mhalf[d,c]
        // 1) dump C-tile to Bs[d][c]; 2) stage z^T chunk into As[d][l]
#pragma unroll
        for (int i = 0; i < 4; ++i)
            *(float4*)&Bs[ty * 4 + i][tx * 4] = acc[i];
        {
            int lz = tid >> 2, gz = tid & 3;
            const float4* zr = (const float4*)&z[(size_t)lz * Dd + m0 + gz * 16];
            float4 z0 = zr[0], z1 = zr[1], z2 = zr[2], z3 = zr[3];
            float* col = &As[gz * 16][lz];
            col[0 * 68] = z0.x; col[1 * 68] = z0.y; col[2 * 68] = z0.z; col[3 * 68] = z0.w;
            col[4 * 68] = z1.x; col[5 * 68] = z1.y; col[6 * 68] = z1.z; col[7 * 68] = z1.w;
            col[8 * 68] = z2.x; col[9 * 68] = z2.y; col[10 * 68] = z2.z; col[11 * 68] = z2.w;
            col[12 * 68] = z3.x; col[13 * 68] = z3.y; col[14 * 68] = z3.z; col[15 * 68] = z3.w;
        }
        __syncthreads();
        // 3) thread owns (l = tid>>2, 16 cols at c0): 64-d dot per col
        {
            int lz = tid >> 2, c0 = (tid & 3) * 16;
            float ap[16];
#pragma unroll
            for (int cc = 0; cc < 16; ++cc) ap[cc] = 0.f;
            for (int dd = 0; dd < 64; ++dd) {
                float zv = As[dd][lz];
                const float4* brow = (const float4*)&Bs[dd][c0];
                float4 b0 = brow[0], b1q = brow[1], b2q = brow[2], b3q = brow[3];
                ap[0]  = fmaf(zv, b0.x,  ap[0]);  ap[1]  = fmaf(zv, b0.y,  ap[1]);
                ap[2]  = fmaf(zv, b0.z,  ap[2]);  ap[3]  = fmaf(zv, b0.w,  ap[3]);
                ap[4]  = fmaf(zv, b1q.x, ap[4]);  ap[5]  = fmaf(zv, b1q.y, ap[5]);
                ap[6]  = fmaf(zv, b1q.z, ap[6]);  ap[7]  = fmaf(zv, b1q.w, ap[7]);
                ap[8]  = fmaf(zv, b2q.x, ap[8]);  ap[9]  = fmaf(zv, b2q.y, ap[9]);
                ap[10] = fmaf(zv, b2q.z, ap[10]); ap[11] = fmaf(zv, b2q.w, ap[11]);
                ap[12] = fmaf(zv, b3q.x, ap[12]); ap[13] = fmaf(zv, b3q.y, ap[13]);
                ap[14] = fmaf(zv, b3q.z, ap[14]); ap[15] = fmaf(zv, b3q.w, ap[15]);
            }
            int j = ((m0 >> 6) << 1) + kh;      // exclusive partial index, 0..15
            float* Pp0 = role01 ? Gp : QKp;
            float* dst = &Pp0[((size_t)j * 64 + lz) * Dd + n0 + c0];
            *(float4*)&dst[0]  = make_float4(ap[0],  ap[1],  ap[2],  ap[3]);
            *(float4*)&dst[4]  = make_float4(ap[4],  ap[5],  ap[6],  ap[7]);
            *(float4*)&dst[8]  = make_float4(ap[8],  ap[9],  ap[10], ap[11]);
            *(float4*)&dst[12] = make_float4(ap[12], ap[13], ap[14], ap[15]);
        }
    } else if (bid < 320) {
        // ---------- WvoT tiles (full K) ----------
        int wb = bid - 256;
        int m0 = (wb >> 3) * 64;
        int n0 = (wb & 7) * 64;
        int tx = tid & 15, ty = tid >> 4;
        float4 acc[4];
#pragma unroll
        for (int i = 0; i < 4; ++i) acc[i] = make_float4(0.f, 0.f, 0.f, 0.f);

        for (int k0 = 0; k0 < Dd; k0 += 64) {
            {
                int kk = tid >> 4, q4 = (tid & 15) * 4;
#pragma unroll
                for (int i = 0; i < 4; ++i) {
                    int k = kk + 16 * i;
                    *(float4*)&As[k][q4] =
                        *(const float4*)&Wv[(size_t)(k0 + k) * Dd + m0 + q4];
                }
                // B = Wo[d][c]: read rows coalesced, transpose-store Bs[c][d]
                int d = tid >> 2;
#pragma unroll
                for (int j = 0; j < 4; ++j) {
                    int c0 = (tid & 3) * 16 + 4 * j;
                    float4 v = *(const float4*)&Wo[(size_t)(n0 + d) * Dd + k0 + c0];
                    Bs[c0 + 0][d] = v.x; Bs[c0 + 1][d] = v.y;
                    Bs[c0 + 2][d] = v.z; Bs[c0 + 3][d] = v.w;
                }
            }
            __syncthreads();
#pragma unroll 8
            for (int kk = 0; kk < 64; ++kk) {
                float4 a4 = *(const float4*)&As[kk][ty * 4];
                float4 b4 = *(const float4*)&Bs[kk][tx * 4];
                acc[0].x = fmaf(a4.x, b4.x, acc[0].x); acc[0].y = fmaf(a4.x, b4.y, acc[0].y);
                acc[0].z = fmaf(a4.x, b4.z, acc[0].z); acc[0].w = fmaf(a4.x, b4.w, acc[0].w);
                acc[1].x = fmaf(a4.y, b4.x, acc[1].x); acc[1].y = fmaf(a4.y, b4.y, acc[1].y);
                acc[1].z = fmaf(a4.y, b4.z, acc[1].z); acc[1].w = fmaf(a4.y, b4.w, acc[1].w);
                acc[2].x = fmaf(a4.z, b4.x, acc[2].x); acc[2].y = fmaf(a4.z, b4.y, acc[2].y);
                acc[2].z = fmaf(a4.z, b4.z, acc[2].z); acc[2].w = fmaf(a4.z, b4.w, acc[2].w);
                acc[3].x = fmaf(a4.w, b4.x, acc[3].x); acc[3].y = fmaf(a4.w, b4.y, acc[3].y);
                acc[3].z = fmaf(a4.w, b4.z, acc[3].z); acc[3].w = fmaf(a4.w, b4.w, acc[3].w);
            }
            __syncthreads();
        }
#pragma unroll
        for (int i = 0; i < 4; ++i)
            *(float4*)&WvoT[(size_t)(m0 + ty * 4 + i) * Dd + n0 + tx * 4] = acc[i];
    } else if (bid < 328) {
        // ---- vb8 partial: e-range [j*64, j*64+64) ----
        int j = bid - 320;
        if (tid < 64) b2s[tid] = b2[j * 64 + tid];
        __syncthreads();
        float a0 = 0.f, a1 = 0.f;
#pragma unroll 4
        for (int ee = 0; ee < 64; ++ee) {
            int e = j * 64 + ee;
            float be = b2s[ee];
            a0 = fmaf(be, Wq[(size_t)e * Dd + tid], a0);
            a1 = fmaf(be, Wq[(size_t)e * Dd + tid + 256], a1);
        }
        vb8[j * Dd + tid] = a0;
        vb8[j * Dd + tid + 256] = a1;
    } else {
        // ---- coord stats ----
        int b = bid - 328;
        double sx = 0, sy = 0, sxx = 0, syy = 0;
        const float4* cp = (const float4*)(coords + (size_t)b * Nn * 2);
        for (int i = tid; i < Nn / 2; i += 256) {      // 2 points per float4
            float4 v = cp[i];
            sx  += (double)v.x + (double)v.z;
            sy  += (double)v.y + (double)v.w;
            sxx += (double)v.x * v.x + (double)v.z * v.z;
            syy += (double)v.y * v.y + (double)v.w * v.w;
        }
        for (int o = 32; o > 0; o >>= 1) {
            sx  += __shfl_down(sx,  o); sy  += __shfl_down(sy,  o);
            sxx += __shfl_down(sxx, o); syy += __shfl_down(syy, o);
        }
        if (lane == 0) {
            dred[wv * 4 + 0] = sx;  dred[wv * 4 + 1] = sy;
            dred[wv * 4 + 2] = sxx; dred[wv * 4 + 3] = syy;
        }
        __syncthreads();
        if (tid == 0) {
            double tx = 0, ty = 0, txx = 0, tyy = 0;
            for (int i = 0; i < 4; ++i) {
                tx += dred[i * 4 + 0]; ty += dred[i * 4 + 1];
                txx += dred[i * 4 + 2]; tyy += dred[i * 4 + 3];
            }
            const double N = (double)Nn;
            double mux = tx / N, muy = ty / N;
            double vx = (txx - N * mux * mux) / (N - 1.0);
            double vy = (tyy - N * muy * muy) / (N - 1.0);
            cstats[b * 4 + 0] = (float)mux;
            cstats[b * 4 + 1] = (float)muy;
            cstats[b * 4 + 2] = (float)sqrt(vx) + 1e-8f;
            cstats[b * 4 + 3] = (float)sqrt(vy) + 1e-8f;
        }
    }
}

// ---------------------------------------------------------------------------
// Fused attention + output projection: one block per (b,l), 1024 threads.
// R12 body; the prologue folds 16 exclusive partials (K-split) for QK/G and
// computes sqk_l / qb2_l in-block via the staging shuffle reduce.
__global__ __launch_bounds__(1024) void attn2(
    const float* __restrict__ feats, const float* __restrict__ coords,
    const float* __restrict__ cstats,
    const float* __restrict__ QKp, const float* __restrict__ Gp,
    const float* __restrict__ vb8, const float* __restrict__ z,
    const float* __restrict__ W1, const float* __restrict__ b1,
    const float* __restrict__ WvoT, const float* __restrict__ bo,
    float* __restrict__ out) {
    __shared__ float  qk_s[Dd];             // QK row; later reused as fm
    __shared__ float4 wpack[Dd + 8];        // {w1a, w1b, b1, g}, WPI-padded
    __shared__ float  scx[Pp], scy[Pp];
    __shared__ float  smu[Pp], srs[Pp], sa[Pp];
    __shared__ float  shs[NW * Ww];
    __shared__ float  sar[NW][Ww];
    __shared__ float  swt[Pp];
    __shared__ float  s2red[NW];
    __shared__ float  soff;
    __shared__ float  redsc[16];            // sqk partials [0..7], qb2 [8..15]
    __shared__ float  red16[16][Dd];        // pass-2 partials; rows 0..7 reused by tail

    int bx = blockIdx.x;                    // b*64 + l
    int l = bx & 63, b = bx >> 6;
    int tid = threadIdx.x;
    int wv = tid >> 6, lane = tid & 63;     // 16 waves

    // ---- stage (global -> LDS); fold 16 partials; sqk/qb2 wave partials ----
    if (tid < Dd) {
        float vq = 0.f;
#pragma unroll
        for (int j = 0; j < 16; ++j)
            vq += QKp[((size_t)j * 64 + l) * Dd + tid];
        qk_s[tid] = vq;
        float vb = 0.f;
#pragma unroll
        for (int j = 0; j < 8; ++j) vb += vb8[j * Dd + tid];
        float pb = z[(size_t)l * Dd + tid] * vb;
        for (int o = 32; o > 0; o >>= 1) {
            vq += __shfl_xor(vq, o); pb += __shfl_xor(pb, o);
        }
        if (lane == 0) { redsc[wv] = vq; redsc[8 + wv] = pb; }
    } else {
        int t = tid - Dd;
        float vg = 0.f;
#pragma unroll
        for (int j = 0; j < 16; ++j)
            vg += Gp[((size_t)j * 64 + l) * Dd + t];
        wpack[WPI(t)] = make_float4(W1[2 * t], W1[2 * t + 1], b1[t], vg);
    }
    if (tid < Pp) {
        int row = bx * Pp + tid;
        float x = coords[(size_t)row * 2], y = coords[(size_t)row * 2 + 1];
        scx[tid] = (x - cstats[b * 4 + 0]) / cstats[b * 4 + 2];
        scy[tid] = (y - cstats[b * 4 + 1]) / cstats[b * 4 + 3];
    }
    __syncthreads();
    float sqk_l = redsc[0] + redsc[1] + redsc[2] + redsc[3]
                + redsc[4] + redsc[5] + redsc[6] + redsc[7];
    float qb2_l = redsc[8] + redsc[9] + redsc[10] + redsc[11]
                + redsc[12] + redsc[13] + redsc[14] + redsc[15];

    // ---- issue ALL feats loads (8 rows/wave) ----
    const float* fbase = feats + (size_t)bx * Pp * Dd;
    int rb = wv * 8;
    float4 f0[8], f1[8];
#pragma unroll
    for (int i = 0; i < 8; ++i) {
        const float4* fr = (const float4*)(fbase + (size_t)(rb + i) * Dd);
        f0[i] = fr[lane];
        f1[i] = fr[lane + 64];
    }
    __builtin_amdgcn_sched_barrier(0);      // pin: loads stay above pos-bias

    // ---- window coord means, per-wave in registers (no barrier) ----
    float cmx[4], cmy[4];
#pragma unroll
    for (int n = 0; n < 4; ++n) {
        int nv = (n == 3) ? 32 : 64;
        float cx = (lane < nv) ? scx[n * Ss + lane] : 0.f;
        float cy = (lane < nv) ? scy[n * Ss + lane] : 0.f;
        for (int o = 32; o > 0; o >>= 1) { cx += __shfl_xor(cx, o); cy += __shfl_xor(cy, o); }
        cmx[n] = cx / (float)nv; cmy[n] = cy / (float)nv;
    }

    // ---- pos-bias (LDS phase; HBM loads stream underneath) ----
    {
        int s = tid >> 2, q = tid & 3;
        int n = s >> 6, w = s & 63;
        int nv = (n == 3) ? 32 : 64;
        float hs = 0.f;
        if (w < nv) {
            int p = n * Ss + w;
            float px = scx[p] - cmx[n], py = scy[p] - cmy[n];
            int d0 = q * 128;
#pragma unroll 4
            for (int i = 0; i < 128; ++i) {
                float4 c = wpack[WPI(d0) + i];   // = wpack[q*130 + i], affine
                hs = fmaf(c.w, fmaxf(fmaf(c.x, px, fmaf(c.y, py, c.z)), 0.f), hs);
            }
        }
        hs += __shfl_xor(hs, 1);
        hs += __shfl_xor(hs, 2);
        if (q == 0) shs[s] = hs;
    }

    // ---- row stats from registers (consumes the loads) ----
    {
        float4 q0 = ((const float4*)qk_s)[lane];
        float4 q1 = ((const float4*)qk_s)[lane + 64];
#pragma unroll
        for (int b2i = 0; b2i < 8; b2i += 4) {
            float sP[4], ssP[4], aP[4];
#pragma unroll
            for (int i = 0; i < 4; ++i) {
                float4 v0 = f0[b2i + i], v1 = f1[b2i + i];
                sP[i]  = v0.x + v0.y + v0.z + v0.w + v1.x + v1.y + v1.z + v1.w;
                ssP[i] = v0.x * v0.x + v0.y * v0.y + v0.z * v0.z + v0.w * v0.w
                       + v1.x * v1.x + v1.y * v1.y + v1.z * v1.z + v1.w * v1.w;
                aP[i]  = v0.x * q0.x + v0.y * q0.y + v0.z * q0.z + v0.w * q0.w
                       + v1.x * q1.x + v1.y * q1.y + v1.z * q1.z + v1.w * q1.w;
            }
#pragma unroll
            for (int o = 32; o > 0; o >>= 1) {
#pragma unroll
                for (int i = 0; i < 4; ++i) {
                    sP[i] += __shfl_xor(sP[i], o); ssP[i] += __shfl_xor(ssP[i], o);
                    aP[i] += __shfl_xor(aP[i], o);
                }
            }
            if (lane == 0) {
#pragma unroll
                for (int i = 0; i < 4; ++i) {
                    int r = rb + b2i + i;
                    float mu  = sP[i] * (1.f / (float)Dd);
                    float var = ssP[i] * (1.f / (float)Dd) - mu * mu;
                    smu[r] = mu; srs[r] = 1.f / sqrtf(var + 1e-5f); sa[r] = aP[i];
                }
            }
        }
    }
    __syncthreads();

    // ---- softmax per window (waves 0..3) ----
    const float invtemp = 0.04419417382415922f; // 1/sqrt(512)
    if (wv < 4) {
        int n = wv, w = lane;
        int nv = (n == 3) ? 32 : 64;
        int p = n * Ss + ((w < nv) ? w : 0);
        float lg = -1e30f;
        if (w < nv) {
            lg = (srs[p] * (sa[p] - smu[p] * sqk_l) + shs[n * Ww + w] + qb2_l) * invtemp;
            lg = fminf(fmaxf(lg, -10.f), 10.f);
        }
        float m = lg;
        for (int o = 32; o > 0; o >>= 1) m = fmaxf(m, __shfl_xor(m, o));
        float e = (w < nv) ? expf(lg - m) : 0.f;
        float ssum = e;
        for (int o = 32; o > 0; o >>= 1) ssum += __shfl_xor(ssum, o);
        float ar = (w < nv) ? (e / ssum) * srs[p] : 0.f;
        sar[n][w] = ar;
        float t2 = (w < nv) ? ar * smu[p] : 0.f;
        for (int o = 32; o > 0; o >>= 1) t2 += __shfl_xor(t2, o);
        if (lane == 0) s2red[n] = t2;
    }
    __syncthreads();

    // ---- combine per-row weights across (<=2) covering windows ----
    if (tid < Pp) {
        int p = tid;
        int na = (p >> 5) - 1, nb = (p >> 5);
        float wt = 0.f;
        if (na >= 0 && na <= 3) wt += sar[na][p - na * Ss];
        if (nb <= 3)            wt += sar[nb][p - nb * Ss];
        swt[p] = wt;
    }
    if (tid == 0) soff = 0.25f * (s2red[0] + s2red[1] + s2red[2] + s2red[3]);
    __syncthreads();

    // ---- pass 2: weighted feature sum FROM REGISTERS ----
    {
        float4 a0 = make_float4(0.f, 0.f, 0.f, 0.f);
        float4 a1 = make_float4(0.f, 0.f, 0.f, 0.f);
#pragma unroll
        for (int i = 0; i < 8; ++i) {
            float wt = swt[rb + i];         // wave-uniform LDS broadcast
            a0.x = fmaf(wt, f0[i].x, a0.x); a0.y = fmaf(wt, f0[i].y, a0.y);
            a0.z = fmaf(wt, f0[i].z, a0.z); a0.w = fmaf(wt, f0[i].w, a0.w);
            a1.x = fmaf(wt, f1[i].x, a1.x); a1.y = fmaf(wt, f1[i].y, a1.y);
            a1.z = fmaf(wt, f1[i].z, a1.z); a1.w = fmaf(wt, f1[i].w, a1.w);
        }
        *(float4*)&red16[wv][lane * 4]       = a0;
        *(float4*)&red16[wv][256 + lane * 4] = a1;
    }
    __syncthreads();
    if (tid < Dd) {
        float v = 0.f;
#pragma unroll
        for (int w = 0; w < 16; ++w) v += red16[w][tid];
        qk_s[tid] = 0.25f * v - soff;       // qk_s reused as fm
    }
    __syncthreads();

    // ---- tail: out = fm @ WvoT + bo (coalesced, L2-resident WvoT) ----
    {
        int h = tid >> 7, cq = (tid & 127) * 4; // 8 e-groups of 64
        float4 acc = make_float4(0.f, 0.f, 0.f, 0.f);
#pragma unroll 4
        for (int e = h * 64; e < h * 64 + 64; ++e) {
            float fe = qk_s[e];
            float4 w = *(const float4*)&WvoT[(size_t)e * Dd + cq];
            acc.x = fmaf(fe, w.x, acc.x);
            acc.y = fmaf(fe, w.y, acc.y);
            acc.z = fmaf(fe, w.z, acc.z);
            acc.w = fmaf(fe, w.w, acc.w);
        }
        *(float4*)&red16[h][cq] = acc;
    }
    __syncthreads();
    if (tid < Dd) {
        out[(size_t)bx * Dd + tid] = bo[tid]
            + red16[0][tid] + red16[1][tid] + red16[2][tid] + red16[3][tid]
            + red16[4][tid] + red16[5][tid] + red16[6][tid] + red16[7][tid];
    }
}

// ---------------------------------------------------------------------------
extern "C" void kernel_launch(void* const* d_in, const int* in_sizes, int n_in,
                              void* d_out, int out_size, void* d_ws, size_t ws_size,
                              hipStream_t stream) {
    const float* feats  = (const float*)d_in[0];
    const float* coords = (const float*)d_in[1];
    // d_in[2] = mask, unused (all false, and unused by the reference body)
    const float* z  = (const float*)d_in[3];
    const float* Wq = (const float*)d_in[4];
    const float* Wk = (const float*)d_in[5];
    const float* Wv = (const float*)d_in[6];
    const float* W1 = (const float*)d_in[7];
    const float* b1 = (const float*)d_in[8];
    const float* W2 = (const float*)d_in[9];
    const float* b2 = (const float*)d_in[10];
    const float* Wo = (const float*)d_in[11];
    const float* bo = (const float*)d_in[12];
    float* out = (float*)d_out;

    // workspace layout (floats) — nothing needs pre-zeroing (~5.2 MB)
    float* ws = (float*)d_ws;
    float* cstats = ws;                         // 16
    float* WvoT   = ws + 16;                    // 512*512
    float* vb8    = WvoT + Dd * Dd;             // 8*512
    float* QKp    = vb8 + 8 * Dd;               // 16*64*512 exclusive partials
    float* Gp     = QKp + 16 * Ll * Dd;         // 16*64*512

    pre1<<<332, 256, 0, stream>>>(coords, b2, Wq, Wk, W2, Wv, Wo, z,
                                  cstats, QKp, Gp, WvoT, vb8);
    attn2<<<Bz * Ll, 1024, 0, stream>>>(feats, coords, cstats,
                                        QKp, Gp, vb8, z, W1, b1,
                                        WvoT, bo, out);
}

// Round 14
// 161.366 us; speedup vs baseline: 1.0193x; 1.0193x over previous
//
#include <hip/hip_runtime.h>

// Sizes fixed by the problem.
#define Bz 4
#define Nn 8192
#define Dd 512
#define Ll 64
#define Pp 128
#define Ww 64
#define Ss 32
#define NW 4   // number of window starts per segment

// wpack bank-conflict pad (R9, proven): lanes q=0..3 read d in {i,128+i,...};
// padded byte base 16*(130q+i) -> disjoint bank groups.
#define WPI(d) ((d) + 2 * ((d) >> 7))

// ---------------------------------------------------------------------------
// pre1: fully parallel preprocessing, 204 blocks x 256 threads.
//   [0,64):    QKp[j][l][c] partials of z @ (Wq^T Wk)  (tile kept in LDS,
//              M1 never stored; each block writes its exclusive j=m0/64 slice)
//   [64,128):  Gp[j][l][c] partials of z @ (Wq^T W2)
//   [128,192): WvoT[e,d] = sum_c Wv[c,e] Wo[d,c]
//   [192,200): vb8[j] = partial Wq^T @ b2
//   [200,204): per-batch coord stats (mean + std ddof=1)
__global__ __launch_bounds__(256) void pre1(
    const float* __restrict__ coords, const float* __restrict__ b2,
    const float* __restrict__ Wq, const float* __restrict__ Wk,
    const float* __restrict__ W2,
    const float* __restrict__ Wv, const float* __restrict__ Wo,
    const float* __restrict__ z,
    float* __restrict__ cstats,
    float* __restrict__ QKp, float* __restrict__ Gp,
    float* __restrict__ WvoT, float* __restrict__ vb8) {
    __shared__ float As[64][68];    // [k][m], 272B rows (16B-aligned)
    __shared__ float Bs[64][68];    // [k][n]; post-loop: holds the C-tile
    __shared__ float b2s[64];
    __shared__ double dred[16];
    int bid = blockIdx.x, tid = threadIdx.x;
    int wv = tid >> 6, lane = tid & 63;

    if (bid < 192) {
        int role = bid >> 6;            // 0=QKp(M1), 1=Gp(M2), 2=WvoT
        int wb = bid & 63;
        int m0 = (wb >> 3) * 64;
        int n0 = (wb & 7) * 64;
        const float* Amat = (role == 2) ? Wv : Wq;
        const float* Bmat = (role == 0) ? Wk : (role == 1) ? W2 : Wo;
        int tx = tid & 15, ty = tid >> 4;       // 16x16 thread grid, 4x4 each
        float4 acc[4];
#pragma unroll
        for (int i = 0; i < 4; ++i) acc[i] = make_float4(0.f, 0.f, 0.f, 0.f);

        for (int k0 = 0; k0 < Dd; k0 += 64) {
            {
                int kk = tid >> 4, q4 = (tid & 15) * 4;
#pragma unroll
                for (int i = 0; i < 4; ++i) {
                    int k = kk + 16 * i;
                    *(float4*)&As[k][q4] =
                        *(const float4*)&Amat[(size_t)(k0 + k) * Dd + m0 + q4];
                }
                if (role != 2) {
#pragma unroll
                    for (int i = 0; i < 4; ++i) {
                        int k = kk + 16 * i;
                        *(float4*)&Bs[k][q4] =
                            *(const float4*)&Bmat[(size_t)(k0 + k) * Dd + n0 + q4];
                    }
                } else {
                    // B = Wo[d][c]: read rows coalesced, transpose-store Bs[c][d]
                    int d = tid >> 2;
#pragma unroll
                    for (int j = 0; j < 4; ++j) {
                        int c0 = (tid & 3) * 16 + 4 * j;
                        float4 v = *(const float4*)&Bmat[(size_t)(n0 + d) * Dd + k0 + c0];
                        Bs[c0 + 0][d] = v.x; Bs[c0 + 1][d] = v.y;
                        Bs[c0 + 2][d] = v.z; Bs[c0 + 3][d] = v.w;
                    }
                }
            }
            __syncthreads();
#pragma unroll 8
            for (int kk = 0; kk < 64; ++kk) {
                float4 a4 = *(const float4*)&As[kk][ty * 4];
                float4 b4 = *(const float4*)&Bs[kk][tx * 4];
                acc[0].x = fmaf(a4.x, b4.x, acc[0].x); acc[0].y = fmaf(a4.x, b4.y, acc[0].y);
                acc[0].z = fmaf(a4.x, b4.z, acc[0].z); acc[0].w = fmaf(a4.x, b4.w, acc[0].w);
                acc[1].x = fmaf(a4.y, b4.x, acc[1].x); acc[1].y = fmaf(a4.y, b4.y, acc[1].y);
                acc[1].z = fmaf(a4.y, b4.z, acc[1].z); acc[1].w = fmaf(a4.y, b4.w, acc[1].w);
                acc[2].x = fmaf(a4.z, b4.x, acc[2].x); acc[2].y = fmaf(a4.z, b4.y, acc[2].y);
                acc[2].z = fmaf(a4.z, b4.z, acc[2].z); acc[2].w = fmaf(a4.z, b4.w, acc[2].w);
                acc[3].x = fmaf(a4.w, b4.x, acc[3].x); acc[3].y = fmaf(a4.w, b4.y, acc[3].y);
                acc[3].z = fmaf(a4.w, b4.z, acc[3].z); acc[3].w = fmaf(a4.w, b4.w, acc[3].w);
            }
            __syncthreads();
        }
        if (role == 2) {
#pragma unroll
            for (int i = 0; i < 4; ++i)
                *(float4*)&WvoT[(size_t)(m0 + ty * 4 + i) * Dd + n0 + tx * 4] = acc[i];
        } else {
            // ---- z-weighted partial: P[l, n0+c] = sum_{d in tile} z[l,d] M[d,c]
            // 1) dump C-tile to Bs[d][c]; 2) stage z^T chunk into As[d][l]
#pragma unroll
            for (int i = 0; i < 4; ++i)
                *(float4*)&Bs[ty * 4 + i][tx * 4] = acc[i];
            {
                int lz = tid >> 2, gz = tid & 3;
                const float4* zr = (const float4*)&z[(size_t)lz * Dd + m0 + gz * 16];
                float4 z0 = zr[0], z1 = zr[1], z2 = zr[2], z3 = zr[3];
                float* col = &As[gz * 16][lz];
                col[0 * 68] = z0.x; col[1 * 68] = z0.y; col[2 * 68] = z0.z; col[3 * 68] = z0.w;
                col[4 * 68] = z1.x; col[5 * 68] = z1.y; col[6 * 68] = z1.z; col[7 * 68] = z1.w;
                col[8 * 68] = z2.x; col[9 * 68] = z2.y; col[10 * 68] = z2.z; col[11 * 68] = z2.w;
                col[12 * 68] = z3.x; col[13 * 68] = z3.y; col[14 * 68] = z3.z; col[15 * 68] = z3.w;
            }
            __syncthreads();
            // 3) thread owns (l = tid>>2, 16 cols at c0): 64-d dot per col
            {
                int lz = tid >> 2, c0 = (tid & 3) * 16;
                float ap[16];
#pragma unroll
                for (int cc = 0; cc < 16; ++cc) ap[cc] = 0.f;
                for (int dd = 0; dd < 64; ++dd) {
                    float zv = As[dd][lz];
                    const float4* brow = (const float4*)&Bs[dd][c0];
                    float4 b0 = brow[0], b1q = brow[1], b2q = brow[2], b3q = brow[3];
                    ap[0]  = fmaf(zv, b0.x,  ap[0]);  ap[1]  = fmaf(zv, b0.y,  ap[1]);
                    ap[2]  = fmaf(zv, b0.z,  ap[2]);  ap[3]  = fmaf(zv, b0.w,  ap[3]);
                    ap[4]  = fmaf(zv, b1q.x, ap[4]);  ap[5]  = fmaf(zv, b1q.y, ap[5]);
                    ap[6]  = fmaf(zv, b1q.z, ap[6]);  ap[7]  = fmaf(zv, b1q.w, ap[7]);
                    ap[8]  = fmaf(zv, b2q.x, ap[8]);  ap[9]  = fmaf(zv, b2q.y, ap[9]);
                    ap[10] = fmaf(zv, b2q.z, ap[10]); ap[11] = fmaf(zv, b2q.w, ap[11]);
                    ap[12] = fmaf(zv, b3q.x, ap[12]); ap[13] = fmaf(zv, b3q.y, ap[13]);
                    ap[14] = fmaf(zv, b3q.z, ap[14]); ap[15] = fmaf(zv, b3q.w, ap[15]);
                }
                float* Pp0 = (role == 0) ? QKp : Gp;
                float* dst = &Pp0[(((size_t)(m0 >> 6)) * 64 + lz) * Dd + n0 + c0];
                *(float4*)&dst[0]  = make_float4(ap[0],  ap[1],  ap[2],  ap[3]);
                *(float4*)&dst[4]  = make_float4(ap[4],  ap[5],  ap[6],  ap[7]);
                *(float4*)&dst[8]  = make_float4(ap[8],  ap[9],  ap[10], ap[11]);
                *(float4*)&dst[12] = make_float4(ap[12], ap[13], ap[14], ap[15]);
            }
        }
    } else if (bid < 200) {
        // ---- vb8 partial: e-range [j*64, j*64+64) ----
        int j = bid - 192;
        if (tid < 64) b2s[tid] = b2[j * 64 + tid];
        __syncthreads();
        float a0 = 0.f, a1 = 0.f;
#pragma unroll 4
        for (int ee = 0; ee < 64; ++ee) {
            int e = j * 64 + ee;
            float be = b2s[ee];
            a0 = fmaf(be, Wq[(size_t)e * Dd + tid], a0);
            a1 = fmaf(be, Wq[(size_t)e * Dd + tid + 256], a1);
        }
        vb8[j * Dd + tid] = a0;
        vb8[j * Dd + tid + 256] = a1;
    } else {
        // ---- coord stats ----
        int b = bid - 200;
        double sx = 0, sy = 0, sxx = 0, syy = 0;
        const float4* cp = (const float4*)(coords + (size_t)b * Nn * 2);
        for (int i = tid; i < Nn / 2; i += 256) {      // 2 points per float4
            float4 v = cp[i];
            sx  += (double)v.x + (double)v.z;
            sy  += (double)v.y + (double)v.w;
            sxx += (double)v.x * v.x + (double)v.z * v.z;
            syy += (double)v.y * v.y + (double)v.w * v.w;
        }
        for (int o = 32; o > 0; o >>= 1) {
            sx  += __shfl_down(sx,  o); sy  += __shfl_down(sy,  o);
            sxx += __shfl_down(sxx, o); syy += __shfl_down(syy, o);
        }
        if (lane == 0) {
            dred[wv * 4 + 0] = sx;  dred[wv * 4 + 1] = sy;
            dred[wv * 4 + 2] = sxx; dred[wv * 4 + 3] = syy;
        }
        __syncthreads();
        if (tid == 0) {
            double tx = 0, ty = 0, txx = 0, tyy = 0;
            for (int i = 0; i < 4; ++i) {
                tx += dred[i * 4 + 0]; ty += dred[i * 4 + 1];
                txx += dred[i * 4 + 2]; tyy += dred[i * 4 + 3];
            }
            const double N = (double)Nn;
            double mux = tx / N, muy = ty / N;
            double vx = (txx - N * mux * mux) / (N - 1.0);
            double vy = (tyy - N * muy * muy) / (N - 1.0);
            cstats[b * 4 + 0] = (float)mux;
            cstats[b * 4 + 1] = (float)muy;
            cstats[b * 4 + 2] = (float)sqrt(vx) + 1e-8f;
            cstats[b * 4 + 3] = (float)sqrt(vy) + 1e-8f;
        }
    }
}

// ---------------------------------------------------------------------------
// Fused attention + output projection: one block per (b,l), 1024 threads.
// R9 body, with the qkg kernel absorbed into the prologue: QK/G rows are
// summed from the 8 exclusive partials (L2-resident), and sqk_l / qb2_l are
// computed in-block via the shuffle reduce the staging already pays for.
__global__ __launch_bounds__(1024) void attn2(
    const float* __restrict__ feats, const float* __restrict__ coords,
    const float* __restrict__ cstats,
    const float* __restrict__ QKp, const float* __restrict__ Gp,
    const float* __restrict__ vb8, const float* __restrict__ z,
    const float* __restrict__ W1, const float* __restrict__ b1,
    const float* __restrict__ WvoT, const float* __restrict__ bo,
    float* __restrict__ out) {
    __shared__ float  qk_s[Dd];             // QK row; later reused as fm
    __shared__ float4 wpack[Dd + 8];        // {w1a, w1b, b1, g}, WPI-padded
    __shared__ float  scx[Pp], scy[Pp];
    __shared__ float  smu[Pp], srs[Pp], sa[Pp];
    __shared__ float  shs[NW * Ww];
    __shared__ float  sar[NW][Ww];
    __shared__ float  swt[Pp];
    __shared__ float  s2red[NW];
    __shared__ float  soff;
    __shared__ float  redsc[16];            // sqk partials [0..7], qb2 [8..15]
    __shared__ float  red16[16][Dd];        // pass-2 partials; rows 0..7 reused by tail

    int bx = blockIdx.x;                    // b*64 + l
    int l = bx & 63, b = bx >> 6;
    int tid = threadIdx.x;
    int wv = tid >> 6, lane = tid & 63;     // 16 waves

    // ---- stage (global -> LDS); fold 8 partials; sqk/qb2 wave partials ----
    if (tid < Dd) {
        float vq = 0.f;
#pragma unroll
        for (int j = 0; j < 8; ++j)
            vq += QKp[((size_t)j * 64 + l) * Dd + tid];
        qk_s[tid] = vq;
        float vb = 0.f;
#pragma unroll
        for (int j = 0; j < 8; ++j) vb += vb8[j * Dd + tid];
        float pb = z[(size_t)l * Dd + tid] * vb;
        for (int o = 32; o > 0; o >>= 1) {
            vq += __shfl_xor(vq, o); pb += __shfl_xor(pb, o);
        }
        if (lane == 0) { redsc[wv] = vq; redsc[8 + wv] = pb; }
    } else {
        int t = tid - Dd;
        float vg = 0.f;
#pragma unroll
        for (int j = 0; j < 8; ++j)
            vg += Gp[((size_t)j * 64 + l) * Dd + t];
        wpack[WPI(t)] = make_float4(W1[2 * t], W1[2 * t + 1], b1[t], vg);
    }
    if (tid < Pp) {
        int row = bx * Pp + tid;
        float x = coords[(size_t)row * 2], y = coords[(size_t)row * 2 + 1];
        scx[tid] = (x - cstats[b * 4 + 0]) / cstats[b * 4 + 2];
        scy[tid] = (y - cstats[b * 4 + 1]) / cstats[b * 4 + 3];
    }
    __syncthreads();
    float sqk_l = redsc[0] + redsc[1] + redsc[2] + redsc[3]
                + redsc[4] + redsc[5] + redsc[6] + redsc[7];
    float qb2_l = redsc[8] + redsc[9] + redsc[10] + redsc[11]
                + redsc[12] + redsc[13] + redsc[14] + redsc[15];

    // ---- issue ALL feats loads (8 rows/wave) ----
    const float* fbase = feats + (size_t)bx * Pp * Dd;
    int rb = wv * 8;
    float4 f0[8], f1[8];
#pragma unroll
    for (int i = 0; i < 8; ++i) {
        const float4* fr = (const float4*)(fbase + (size_t)(rb + i) * Dd);
        f0[i] = fr[lane];
        f1[i] = fr[lane + 64];
    }
    __builtin_amdgcn_sched_barrier(0);      // pin: loads stay above pos-bias

    // ---- window coord means, per-wave in registers (no barrier) ----
    float cmx[4], cmy[4];
#pragma unroll
    for (int n = 0; n < 4; ++n) {
        int nv = (n == 3) ? 32 : 64;
        float cx = (lane < nv) ? scx[n * Ss + lane] : 0.f;
        float cy = (lane < nv) ? scy[n * Ss + lane] : 0.f;
        for (int o = 32; o > 0; o >>= 1) { cx += __shfl_xor(cx, o); cy += __shfl_xor(cy, o); }
        cmx[n] = cx / (float)nv; cmy[n] = cy / (float)nv;
    }

    // ---- pos-bias (LDS phase; HBM loads stream underneath) ----
    {
        int s = tid >> 2, q = tid & 3;
        int n = s >> 6, w = s & 63;
        int nv = (n == 3) ? 32 : 64;
        float hs = 0.f;
        if (w < nv) {
            int p = n * Ss + w;
            float px = scx[p] - cmx[n], py = scy[p] - cmy[n];
            int d0 = q * 128;
#pragma unroll 4
            for (int i = 0; i < 128; ++i) {
                float4 c = wpack[WPI(d0) + i];   // = wpack[q*130 + i], affine
                hs = fmaf(c.w, fmaxf(fmaf(c.x, px, fmaf(c.y, py, c.z)), 0.f), hs);
            }
        }
        hs += __shfl_xor(hs, 1);
        hs += __shfl_xor(hs, 2);
        if (q == 0) shs[s] = hs;
    }

    // ---- row stats from registers (consumes the loads) ----
    {
        float4 q0 = ((const float4*)qk_s)[lane];
        float4 q1 = ((const float4*)qk_s)[lane + 64];
#pragma unroll
        for (int b2i = 0; b2i < 8; b2i += 4) {
            float sP[4], ssP[4], aP[4];
#pragma unroll
            for (int i = 0; i < 4; ++i) {
                float4 v0 = f0[b2i + i], v1 = f1[b2i + i];
                sP[i]  = v0.x + v0.y + v0.z + v0.w + v1.x + v1.y + v1.z + v1.w;
                ssP[i] = v0.x * v0.x + v0.y * v0.y + v0.z * v0.z + v0.w * v0.w
                       + v1.x * v1.x + v1.y * v1.y + v1.z * v1.z + v1.w * v1.w;
                aP[i]  = v0.x * q0.x + v0.y * q0.y + v0.z * q0.z + v0.w * q0.w
                       + v1.x * q1.x + v1.y * q1.y + v1.z * q1.z + v1.w * q1.w;
            }
#pragma unroll
            for (int o = 32; o > 0; o >>= 1) {
#pragma unroll
                for (int i = 0; i < 4; ++i) {
                    sP[i] += __shfl_xor(sP[i], o); ssP[i] += __shfl_xor(ssP[i], o);
                    aP[i] += __shfl_xor(aP[i], o);
                }
            }
            if (lane == 0) {
#pragma unroll
                for (int i = 0; i < 4; ++i) {
                    int r = rb + b2i + i;
                    float mu  = sP[i] * (1.f / (float)Dd);
                    float var = ssP[i] * (1.f / (float)Dd) - mu * mu;
                    smu[r] = mu; srs[r] = 1.f / sqrtf(var + 1e-5f); sa[r] = aP[i];
                }
            }
        }
    }
    __syncthreads();

    // ---- softmax per window (waves 0..3) ----
    const float invtemp = 0.04419417382415922f; // 1/sqrt(512)
    if (wv < 4) {
        int n = wv, w = lane;
        int nv = (n == 3) ? 32 : 64;
        int p = n * Ss + ((w < nv) ? w : 0);
        float lg = -1e30f;
        if (w < nv) {
            lg = (srs[p] * (sa[p] - smu[p] * sqk_l) + shs[n * Ww + w] + qb2_l) * invtemp;
            lg = fminf(fmaxf(lg, -10.f), 10.f);
        }
        float m = lg;
        for (int o = 32; o > 0; o >>= 1) m = fmaxf(m, __shfl_xor(m, o));
        float e = (w < nv) ? expf(lg - m) : 0.f;
        float ssum = e;
        for (int o = 32; o > 0; o >>= 1) ssum += __shfl_xor(ssum, o);
        float ar = (w < nv) ? (e / ssum) * srs[p] : 0.f;
        sar[n][w] = ar;
        float t2 = (w < nv) ? ar * smu[p] : 0.f;
        for (int o = 32; o > 0; o >>= 1) t2 += __shfl_xor(t2, o);
        if (lane == 0) s2red[n] = t2;
    }
    __syncthreads();

    // ---- combine per-row weights across (<=2) covering windows ----
    if (tid < Pp) {
        int p = tid;
        int na = (p >> 5) - 1, nb = (p >> 5);
        float wt = 0.f;
        if (na >= 0 && na <= 3) wt += sar[na][p - na * Ss];
        if (nb <= 3)            wt += sar[nb][p - nb * Ss];
        swt[p] = wt;
    }
    if (tid == 0) soff = 0.25f * (s2red[0] + s2red[1] + s2red[2] + s2red[3]);
    __syncthreads();

    // ---- pass 2: weighted feature sum FROM REGISTERS ----
    {
        float4 a0 = make_float4(0.f, 0.f, 0.f, 0.f);
        float4 a1 = make_float4(0.f, 0.f, 0.f, 0.f);
#pragma unroll
        for (int i = 0; i < 8; ++i) {
            float wt = swt[rb + i];         // wave-uniform LDS broadcast
            a0.x = fmaf(wt, f0[i].x, a0.x); a0.y = fmaf(wt, f0[i].y, a0.y);
            a0.z = fmaf(wt, f0[i].z, a0.z); a0.w = fmaf(wt, f0[i].w, a0.w);
            a1.x = fmaf(wt, f1[i].x, a1.x); a1.y = fmaf(wt, f1[i].y, a1.y);
            a1.z = fmaf(wt, f1[i].z, a1.z); a1.w = fmaf(wt, f1[i].w, a1.w);
        }
        *(float4*)&red16[wv][lane * 4]       = a0;
        *(float4*)&red16[wv][256 + lane * 4] = a1;
    }
    __syncthreads();
    if (tid < Dd) {
        float v = 0.f;
#pragma unroll
        for (int w = 0; w < 16; ++w) v += red16[w][tid];
        qk_s[tid] = 0.25f * v - soff;       // qk_s reused as fm
    }
    __syncthreads();

    // ---- tail: out = fm @ WvoT + bo (coalesced, L2-resident WvoT) ----
    {
        int h = tid >> 7, cq = (tid & 127) * 4; // 8 e-groups of 64
        float4 acc = make_float4(0.f, 0.f, 0.f, 0.f);
#pragma unroll 4
        for (int e = h * 64; e < h * 64 + 64; ++e) {
            float fe = qk_s[e];
            float4 w = *(const float4*)&WvoT[(size_t)e * Dd + cq];
            acc.x = fmaf(fe, w.x, acc.x);
            acc.y = fmaf(fe, w.y, acc.y);
            acc.z = fmaf(fe, w.z, acc.z);
            acc.w = fmaf(fe, w.w, acc.w);
        }
        *(float4*)&red16[h][cq] = acc;
    }
    __syncthreads();
    if (tid < Dd) {
        out[(size_t)bx * Dd + tid] = bo[tid]
            + red16[0][tid] + red16[1][tid] + red16[2][tid] + red16[3][tid]
            + red16[4][tid] + red16[5][tid] + red16[6][tid] + red16[7][tid];
    }
}

// ---------------------------------------------------------------------------
extern "C" void kernel_launch(void* const* d_in, const int* in_sizes, int n_in,
                              void* d_out, int out_size, void* d_ws, size_t ws_size,
                              hipStream_t stream) {
    const float* feats  = (const float*)d_in[0];
    const float* coords = (const float*)d_in[1];
    // d_in[2] = mask, unused (all false, and unused by the reference body)
    const float* z  = (const float*)d_in[3];
    const float* Wq = (const float*)d_in[4];
    const float* Wk = (const float*)d_in[5];
    const float* Wv = (const float*)d_in[6];
    const float* W1 = (const float*)d_in[7];
    const float* b1 = (const float*)d_in[8];
    const float* W2 = (const float*)d_in[9];
    const float* b2 = (const float*)d_in[10];
    const float* Wo = (const float*)d_in[11];
    const float* bo = (const float*)d_in[12];
    float* out = (float*)d_out;

    // workspace layout (floats) — nothing needs pre-zeroing (~3.2 MB)
    float* ws = (float*)d_ws;
    float* cstats = ws;                         // 16
    float* WvoT   = ws + 16;                    // 512*512
    float* vb8    = WvoT + Dd * Dd;             // 8*512
    float* QKp    = vb8 + 8 * Dd;               // 8*64*512 exclusive partials
    float* Gp     = QKp + 8 * Ll * Dd;          // 8*64*512

    pre1<<<204, 256, 0, stream>>>(coords, b2, Wq, Wk, W2, Wv, Wo, z,
                                  cstats, QKp, Gp, WvoT, vb8);
    attn2<<<Bz * Ll, 1024, 0, stream>>>(feats, coords, cstats,
                                        QKp, Gp, vb8, z, W1, b1,
                                        WvoT, bo, out);
}